// Round 14
// baseline (31.692 us; speedup 1.0000x reference)
//
#include <hip/hip_runtime.h>
#include <hip/hip_bf16.h>
#include <math.h>

// B=1, H=16, L=2048, D=64. Chunked gated recurrence, chunk C=64, NC=32.
// R13 champion structure (3 dispatches, XCD affinity bid=c*16+h, load-order
// discipline) + this round: k_out is LDS-free and barrier-free — Wprev^T
// B-fragments are loaded DIRECT from global per lane (2 float4 per fragment,
// XCD-local L2-hot) and split hi/lo in registers, like the q A-fragments.
// All 64^3 matmuls: v_mfma_f32_16x16x32_bf16, FULL hi/lo split-bf16 (3-MFMA
// emulation ~2^-17 rel err) on every operand (LN amplifies relative error).
// k_chunk LDS tiles bf16 [64][128B], XOR-swizzled (byte ^= (row&7)<<4).
// A row-major [M][K], B transposed [N][K]: one ds_read_b128 per fragment.
// C/D: row=4*(l>>4)+reg, col=l&15 (m89-verified).

#define H 16
#define L 2048
#define D 64
#define NC 32

typedef short s8v __attribute__((ext_vector_type(8)));
typedef short s4v __attribute__((ext_vector_type(4)));
typedef float f4v __attribute__((ext_vector_type(4)));

__device__ inline unsigned short f2bf(float x) {
  unsigned u = __float_as_uint(x);
  return (unsigned short)((u + 0x7fffu + ((u >> 16) & 1u)) >> 16);
}
__device__ inline float bf2f(unsigned short s) { return __uint_as_float(((unsigned)s) << 16); }

__device__ inline int swz(int row, int colByte) { return row * 128 + (colByte ^ ((row & 7) << 4)); }

__device__ inline s8v ld8(const short* base, int row, int colByte) {
  return *(const s8v*)((const char*)base + swz(row, colByte));
}
__device__ inline void st4(short* base, int row, int colByte, s4v v) {
  *(s4v*)((char*)base + swz(row, colByte)) = v;
}
__device__ inline void st2(short* base, int row, int colByte, unsigned v) {
  *(unsigned*)((char*)base + swz(row, colByte)) = v;
}
__device__ inline void st1(short* base, int row, int colByte, unsigned short v) {
  *(short*)((char*)base + swz(row, colByte)) = (short)v;
}

__device__ inline void red16(float& x) {
  x += __shfl_xor(x, 1, 64);
  x += __shfl_xor(x, 2, 64);
  x += __shfl_xor(x, 4, 64);
  x += __shfl_xor(x, 8, 64);
}

__device__ inline f4v MM(s8v a, s8v b, f4v c) {
  return __builtin_amdgcn_mfma_f32_16x16x32_bf16(a, b, c, 0, 0, 0);
}
// 3-MFMA split product: (Ah+Al)(Bh+Bl) ~= Ah*Bh + Ah*Bl + Al*Bh
__device__ inline f4v MM3(s8v ah, s8v al, s8v bh, s8v bl, f4v c) {
  c = MM(ah, bh, c);
  c = MM(ah, bl, c);
  c = MM(al, bh, c);
  return c;
}

// ---------------- Kernel 1: per-chunk gradl + QK^T + decay + Intra + U^T.
// (unchanged from R13 champion)
__global__ __launch_bounds__(256, 2) void k_chunk(
    const float4* __restrict__ Q4, const float4* __restrict__ K4,
    const float* __restrict__ Kg, const float* __restrict__ Vg,
    const float* __restrict__ gate, const float* __restrict__ eta,
    const float4* __restrict__ W04, const float* __restrict__ gamma,
    const float* __restrict__ beta,
    float* __restrict__ Ut, float* __restrict__ Pg, float* __restrict__ Out)
{
  __shared__ __align__(16) short Khi[4096];
  __shared__ __align__(16) short Klo[4096];
  __shared__ __align__(16) short KtH[4096];
  __shared__ __align__(16) short KtL[4096];
  __shared__ __align__(16) short W0h[4096];
  __shared__ __align__(16) short W0l[4096];
  __shared__ float cl[64], wj[64];

  int tid = threadIdx.x;
  int bid = blockIdx.x;
  int h = bid & 15;            // XCD swizzle: bid%8 == h%8
  int c = bid >> 4;
  int rowb = h * L + c * 64;
  int R = tid >> 6, l = tid & 63, g = l >> 4, c16 = l & 15;
  int arow = 16 * R + c16;
  int kb0 = 16 * g, kb1 = 64 + 16 * g;

  float gv = gate[rowb + l];

  int g4 = tid & 15;
  float4 kA[2][2], wA[2][2];
  #pragma unroll
  for (int it = 0; it < 2; ++it) {
    int j0 = 2 * ((tid >> 4) + it * 16);
    kA[it][0] = K4[(size_t)(rowb + j0) * 16 + g4];
    kA[it][1] = K4[(size_t)(rowb + j0 + 1) * 16 + g4];
    wA[it][0] = W04[(size_t)h * 1024 + j0 * 16 + g4];
    wA[it][1] = W04[(size_t)h * 1024 + (j0 + 1) * 16 + g4];
  }

  const float4* qp = Q4 + (size_t)(rowb + arow) * 16;
  float4 qA0 = qp[2 * g], qA1 = qp[2 * g + 1], qA2 = qp[8 + 2 * g], qA3 = qp[8 + 2 * g + 1];
  float kk[4][4], vv[4][4], er[4];
  #pragma unroll
  for (int r = 0; r < 4; ++r) {
    int jr = 16 * R + 4 * g + r;
    const float* kp = Kg + (size_t)(rowb + jr) * 64 + c16;
    const float* vp = Vg + (size_t)(rowb + jr) * 64 + c16;
    #pragma unroll
    for (int ct = 0; ct < 4; ++ct) {
      kk[r][ct] = kp[16 * ct];
      vv[r][ct] = vp[16 * ct];
    }
    er[r] = eta[rowb + jr];
  }

  {
    float x = logf(fmaxf(gv, 1e-37f));
    #pragma unroll
    for (int off = 1; off < 64; off <<= 1) {
      float n = __shfl_up(x, off, 64);
      if (l >= off) x += n;
    }
    cl[l] = x;
    float c63 = __shfl(x, 63, 64);
    wj[l] = expf(c63 - x);
    if (R == 0) Pg[rowb + l] = expf(x);
  }

  #pragma unroll
  for (int it = 0; it < 2; ++it) {
    int j0 = 2 * ((tid >> 4) + it * 16);
    int j1 = j0 + 1;
    float w0j = wj[j0], w1j = wj[j1];
    float ke0[4] = {kA[it][0].x, kA[it][0].y, kA[it][0].z, kA[it][0].w};
    float ke1[4] = {kA[it][1].x, kA[it][1].y, kA[it][1].z, kA[it][1].w};
    float we0[4] = {wA[it][0].x, wA[it][0].y, wA[it][0].z, wA[it][0].w};
    float we1[4] = {wA[it][1].x, wA[it][1].y, wA[it][1].z, wA[it][1].w};
    s4v kh0, kl0, kh1, kl1;
    #pragma unroll
    for (int e = 0; e < 4; ++e) {
      unsigned short hb0 = f2bf(ke0[e]);
      kh0[e] = (short)hb0; kl0[e] = (short)f2bf(ke0[e] - bf2f(hb0));
      unsigned short hb1 = f2bf(ke1[e]);
      kh1[e] = (short)hb1; kl1[e] = (short)f2bf(ke1[e] - bf2f(hb1));
      int dr = 4 * g4 + e;
      float wk0 = ke0[e] * w0j, wk1 = ke1[e] * w1j;
      unsigned short th0 = f2bf(wk0), th1 = f2bf(wk1);
      st2(KtH, dr, 2 * j0, (unsigned)th0 | ((unsigned)th1 << 16));
      st2(KtL, dr, 2 * j0,
          (unsigned)f2bf(wk0 - bf2f(th0)) | ((unsigned)f2bf(wk1 - bf2f(th1)) << 16));
      unsigned short wh0 = f2bf(we0[e]), wh1 = f2bf(we1[e]);
      st2(W0h, dr, 2 * j0, (unsigned)wh0 | ((unsigned)wh1 << 16));
      st2(W0l, dr, 2 * j0,
          (unsigned)f2bf(we0[e] - bf2f(wh0)) | ((unsigned)f2bf(we1[e] - bf2f(wh1)) << 16));
    }
    st4(Khi, j0, 8 * g4, kh0); st4(Klo, j0, 8 * g4, kl0);
    st4(Khi, j1, 8 * g4, kh1); st4(Klo, j1, 8 * g4, kl1);
  }

  s8v aQh0, aQl0, aQh1, aQl1;
  {
    float q0[8] = {qA0.x, qA0.y, qA0.z, qA0.w, qA1.x, qA1.y, qA1.z, qA1.w};
    float q1[8] = {qA2.x, qA2.y, qA2.z, qA2.w, qA3.x, qA3.y, qA3.z, qA3.w};
    #pragma unroll
    for (int e = 0; e < 8; ++e) {
      unsigned short hb = f2bf(q0[e]);
      aQh0[e] = (short)hb; aQl0[e] = (short)f2bf(q0[e] - bf2f(hb));
      unsigned short hb1 = f2bf(q1[e]);
      aQh1[e] = (short)hb1; aQl1[e] = (short)f2bf(q1[e] - bf2f(hb1));
    }
  }
  __syncthreads();   // bar1: tiles staged

  f4v accS[4];
  #pragma unroll
  for (int ct = 0; ct < 4; ++ct) {
    int br = 16 * ct + c16;
    f4v a = {0.f, 0.f, 0.f, 0.f};
    a = MM3(aQh0, aQl0, ld8(Khi, br, kb0), ld8(Klo, br, kb0), a);
    a = MM3(aQh1, aQl1, ld8(Khi, br, kb1), ld8(Klo, br, kb1), a);
    accS[ct] = a;
  }

  s8v aKh0 = ld8(Khi, arow, kb0), aKh1 = ld8(Khi, arow, kb1);
  s8v aKl0 = ld8(Klo, arow, kb0), aKl1 = ld8(Klo, arow, kb1);
  f4v accZ[4];
  #pragma unroll
  for (int ct = 0; ct < 4; ++ct) {
    int br = 16 * ct + c16;
    f4v a = {0.f, 0.f, 0.f, 0.f};
    a = MM3(aKh0, aKl0, ld8(W0h, br, kb0), ld8(W0l, br, kb0), a);
    a = MM3(aKh1, aKl1, ld8(W0h, br, kb1), ld8(W0l, br, kb1), a);
    accZ[ct] = a;
  }

  float ga[4], be[4];
  #pragma unroll
  for (int ct = 0; ct < 4; ++ct) {
    ga[ct] = gamma[h * 64 + 16 * ct + c16];
    be[ct] = beta[h * 64 + 16 * ct + c16];
  }
  float gtreg[4][4];
  #pragma unroll
  for (int r = 0; r < 4; ++r) {
    float s1 = accZ[0][r] + accZ[1][r] + accZ[2][r] + accZ[3][r];
    red16(s1);
    float mu = s1 * (1.f / 64.f);
    float dv[4], s2 = 0.f;
    #pragma unroll
    for (int ct = 0; ct < 4; ++ct) { dv[ct] = accZ[ct][r] - mu; s2 += dv[ct] * dv[ct]; }
    red16(s2);
    float rstd = rsqrtf(s2 * (1.f / 64.f) + 1e-6f);
    float xh[4], gxh[4], t1 = 0.f, t2 = 0.f;
    #pragma unroll
    for (int ct = 0; ct < 4; ++ct) {
      xh[ct] = dv[ct] * rstd;
      float go = 2.f * (fmaf(ga[ct], xh[ct], be[ct]) + kk[r][ct] - vv[r][ct]);
      gxh[ct] = go * ga[ct];
      t1 += gxh[ct];
      t2 += gxh[ct] * xh[ct];
    }
    red16(t1);
    red16(t2);
    float m1 = t1 * (1.f / 64.f), m2 = t2 * (1.f / 64.f);
    #pragma unroll
    for (int ct = 0; ct < 4; ++ct)
      gtreg[r][ct] = -er[r] * (gxh[ct] - m1 - xh[ct] * m2) * rstd;
  }
  __syncthreads();   // bar2: K-row and W0 tiles dead

  #pragma unroll
  for (int ct = 0; ct < 4; ++ct) {
    s4v gh, gl;
    #pragma unroll
    for (int r = 0; r < 4; ++r) {
      unsigned short hb = f2bf(gtreg[r][ct]);
      gh[r] = (short)hb;
      gl[r] = (short)f2bf(gtreg[r][ct] - bf2f(hb));
    }
    st4(W0h, 16 * ct + c16, 2 * (16 * R + 4 * g), gh);
    st4(W0l, 16 * ct + c16, 2 * (16 * R + 4 * g), gl);
  }
  float cli[4];
  #pragma unroll
  for (int r = 0; r < 4; ++r) cli[r] = cl[16 * R + 4 * g + r];
  #pragma unroll
  for (int ct = 0; ct < 4; ++ct) {
    int j = 16 * ct + c16;
    float clj = cl[j];
    #pragma unroll
    for (int r = 0; r < 4; ++r) {
      int i = 16 * R + 4 * g + r;
      float s = (j <= i) ? accS[ct][r] * expf(cli[r] - clj) : 0.f;
      unsigned short hb = f2bf(s);
      st1(Khi, i, 2 * j, hb);
      st1(Klo, i, 2 * j, f2bf(s - bf2f(hb)));
    }
  }
  __syncthreads();   // bar3: S and gt^T visible

  s8v aSh0 = ld8(Khi, arow, kb0), aSh1 = ld8(Khi, arow, kb1);
  s8v aSl0 = ld8(Klo, arow, kb0), aSl1 = ld8(Klo, arow, kb1);
  #pragma unroll
  for (int ct = 0; ct < 4; ++ct) {
    int br = 16 * ct + c16;
    f4v a = {0.f, 0.f, 0.f, 0.f};
    a = MM3(aSh0, aSl0, ld8(W0h, br, kb0), ld8(W0l, br, kb0), a);
    a = MM3(aSh1, aSl1, ld8(W0h, br, kb1), ld8(W0l, br, kb1), a);
    #pragma unroll
    for (int r = 0; r < 4; ++r)
      Out[(size_t)(rowb + 16 * R + 4 * g + r) * 64 + br] = a[r];
  }

  float* ub = Ut + (size_t)(h * NC + c) * 4096;
  s8v aGh0 = ld8(W0h, arow, kb0), aGh1 = ld8(W0h, arow, kb1);
  s8v aGl0 = ld8(W0l, arow, kb0), aGl1 = ld8(W0l, arow, kb1);
  #pragma unroll
  for (int ct = 0; ct < 4; ++ct) {
    int br = 16 * ct + c16;
    f4v a = {0.f, 0.f, 0.f, 0.f};
    a = MM3(aGh0, aGl0, ld8(KtH, br, kb0), ld8(KtL, br, kb0), a);
    a = MM3(aGh1, aGl1, ld8(KtH, br, kb1), ld8(KtL, br, kb1), a);
    #pragma unroll
    for (int r = 0; r < 4; ++r)
      ub[(16 * R + 4 * g + r) * 64 + br] = a[r];
  }
}

// ---------------- Kernel 2: chunk-state scan, XCD-affine (unchanged from R13).
__global__ __launch_bounds__(256) void k_scan(
    const float* __restrict__ W0, const float* __restrict__ Ut,
    const float* __restrict__ Pg, float* __restrict__ Wpt)
{
  int bid = blockIdx.x;
  int h = bid & 15;
  int part = bid >> 4;
  int idx = part * 256 + threadIdx.x;
  int erow = idx >> 6, d = idx & 63;
  float w = W0[h * 4096 + d * 64 + erow];
  #pragma unroll
  for (int c2 = 0; c2 < NC; ++c2) {
    int off = (h * NC + c2) * 4096 + idx;
    Wpt[off] = w;
    w = fmaf(Pg[h * L + c2 * 64 + 63], w, Ut[off]);
  }
}

// ---------------- Kernel 3: LDS-free, barrier-free readout.
// W^T B-fragments direct from global (XCD-local L2), split hi/lo in regs.
__global__ __launch_bounds__(256, 2) void k_out(
    const float4* __restrict__ Q4, const float* __restrict__ Qg,
    const float* __restrict__ Wpt, const float* __restrict__ Pg,
    const float* __restrict__ gamma, const float* __restrict__ beta,
    float* __restrict__ Out)
{
  int tid = threadIdx.x;
  int bid = blockIdx.x;
  int h = bid & 15;            // same XCD swizzle as k_chunk/k_scan
  int c = bid >> 4;
  int rowb = h * L + c * 64;
  int R = tid >> 6, l = tid & 63, g = l >> 4, c16 = l & 15;
  int arow = 16 * R + c16;

  // ---- W^T fragment loads first: row br = 16ct+c16, elems [8g+32*hf, +8)
  const float* wb = Wpt + (size_t)(h * NC + c) * 4096;
  float4 wf[4][2][2];
  #pragma unroll
  for (int ct = 0; ct < 4; ++ct) {
    const float* wr = wb + (16 * ct + c16) * 64;
    #pragma unroll
    for (int hf = 0; hf < 2; ++hf) {
      int d0 = 8 * g + 32 * hf;
      wf[ct][hf][0] = *(const float4*)(wr + d0);
      wf[ct][hf][1] = *(const float4*)(wr + d0 + 4);
    }
  }

  // ---- q A-fragments + epilogue prefetches
  const float4* qp = Q4 + (size_t)(rowb + arow) * 16;
  float4 qA0 = qp[2 * g], qA1 = qp[2 * g + 1], qA2 = qp[8 + 2 * g], qA3 = qp[8 + 2 * g + 1];
  float io[4][4], qres[4][4], pr[4];
  #pragma unroll
  for (int r = 0; r < 4; ++r) {
    int row = rowb + 16 * R + 4 * g + r;
    pr[r] = Pg[row];
    #pragma unroll
    for (int ct = 0; ct < 4; ++ct) {
      io[r][ct] = Out[(size_t)row * 64 + 16 * ct + c16];
      qres[r][ct] = Qg[(size_t)row * 64 + 16 * ct + c16];
    }
  }

  // ---- split W fragments hi/lo in registers
  s8v bWh[4][2], bWl[4][2];
  #pragma unroll
  for (int ct = 0; ct < 4; ++ct) {
    #pragma unroll
    for (int hf = 0; hf < 2; ++hf) {
      float we[8] = {wf[ct][hf][0].x, wf[ct][hf][0].y, wf[ct][hf][0].z, wf[ct][hf][0].w,
                     wf[ct][hf][1].x, wf[ct][hf][1].y, wf[ct][hf][1].z, wf[ct][hf][1].w};
      s8v wh, wl;
      #pragma unroll
      for (int e = 0; e < 8; ++e) {
        unsigned short hb = f2bf(we[e]);
        wh[e] = (short)hb;
        wl[e] = (short)f2bf(we[e] - bf2f(hb));
      }
      bWh[ct][hf] = wh;
      bWl[ct][hf] = wl;
    }
  }

  // ---- split q A-fragments
  s8v ah0, al0, ah1, al1;
  {
    float q0[8] = {qA0.x, qA0.y, qA0.z, qA0.w, qA1.x, qA1.y, qA1.z, qA1.w};
    float q1[8] = {qA2.x, qA2.y, qA2.z, qA2.w, qA3.x, qA3.y, qA3.z, qA3.w};
    #pragma unroll
    for (int e = 0; e < 8; ++e) {
      unsigned short hb = f2bf(q0[e]);
      ah0[e] = (short)hb; al0[e] = (short)f2bf(q0[e] - bf2f(hb));
      unsigned short hb1 = f2bf(q1[e]);
      ah1[e] = (short)hb1; al1[e] = (short)f2bf(q1[e] - bf2f(hb1));
    }
  }

  f4v acc[4];
  #pragma unroll
  for (int ct = 0; ct < 4; ++ct) {
    f4v a = {0.f, 0.f, 0.f, 0.f};
    a = MM3(ah0, al0, bWh[ct][0], bWl[ct][0], a);
    a = MM3(ah1, al1, bWh[ct][1], bWl[ct][1], a);
    acc[ct] = a;
  }
  float ga[4], be[4];
  #pragma unroll
  for (int ct = 0; ct < 4; ++ct) {
    ga[ct] = gamma[h * 64 + 16 * ct + c16];
    be[ct] = beta[h * 64 + 16 * ct + c16];
  }
  #pragma unroll
  for (int r = 0; r < 4; ++r) {
    int row = rowb + 16 * R + 4 * g + r;
    float zq[4];
    #pragma unroll
    for (int ct = 0; ct < 4; ++ct)
      zq[ct] = fmaf(pr[r], acc[ct][r], io[r][ct]);
    float s1 = zq[0] + zq[1] + zq[2] + zq[3];
    red16(s1);
    float mu = s1 * (1.f / 64.f);
    float dv[4], s2 = 0.f;
    #pragma unroll
    for (int ct = 0; ct < 4; ++ct) { dv[ct] = zq[ct] - mu; s2 += dv[ct] * dv[ct]; }
    red16(s2);
    float rstd = rsqrtf(s2 * (1.f / 64.f) + 1e-6f);
    #pragma unroll
    for (int ct = 0; ct < 4; ++ct) {
      float o = fmaf(ga[ct], dv[ct] * rstd, be[ct]) + qres[r][ct];
      Out[(size_t)row * 64 + 16 * ct + c16] = o;
    }
  }
}

extern "C" void kernel_launch(void* const* d_in, const int* in_sizes, int n_in,
                              void* d_out, int out_size, void* d_ws, size_t ws_size,
                              hipStream_t stream) {
  const float* q     = (const float*)d_in[0];
  const float* k     = (const float*)d_in[1];
  const float* v     = (const float*)d_in[2];
  const float* gate  = (const float*)d_in[3];
  const float* eta   = (const float*)d_in[4];
  const float* W0    = (const float*)d_in[5];
  const float* gamma = (const float*)d_in[6];
  const float* beta  = (const float*)d_in[7];
  float* out = (float*)d_out;
  float* ws  = (float*)d_ws;

  float* Pg  = ws;                         // 32768 floats
  float* Ut  = ws + 32768;                 // 2097152 floats
  float* Wpt = ws + 32768 + 2097152;       // 2097152 floats

  k_chunk<<<H * NC, 256, 0, stream>>>(
      (const float4*)q, (const float4*)k, k, v, gate, eta,
      (const float4*)W0, gamma, beta, Ut, Pg, out);
  k_scan<<<256, 256, 0, stream>>>(W0, Ut, Pg, Wpt);
  k_out<<<H * NC, 256, 0, stream>>>(
      (const float4*)q, q, Wpt, Pg, gamma, beta, out);
}

// Round 15
// 30.103 us; speedup vs baseline: 1.0528x; 1.0528x over previous
//
#include <hip/hip_runtime.h>
#include <hip/hip_bf16.h>
#include <math.h>

// B=1, H=16, L=2048, D=64. Chunked gated recurrence, chunk C=64, NC=32.
// R13 champion (3 dispatches, XCD affinity bid=c*16+h, load-order discipline,
// k_out LDS-staged at 4 blocks/CU) + this round: k_scan hoists all 32 gate
// scalars and 32 Ut values into registers BEFORE the recurrence (the loads are
// address-independent; only the fmaf chain is sequential) — one latency wall
// instead of 32. (R14's LDS-free k_out regressed; reverted.)
// All 64^3 matmuls: v_mfma_f32_16x16x32_bf16, FULL hi/lo split-bf16 (3-MFMA
// emulation ~2^-17 rel err) on every operand (LN amplifies relative error).
// k_chunk LDS tiles bf16 [64][128B], XOR-swizzled (byte ^= (row&7)<<4).
// A row-major [M][K], B transposed [N][K]: one ds_read_b128 per fragment.
// C/D: row=4*(l>>4)+reg, col=l&15 (m89-verified).

#define H 16
#define L 2048
#define D 64
#define NC 32

typedef short s8v __attribute__((ext_vector_type(8)));
typedef short s4v __attribute__((ext_vector_type(4)));
typedef float f4v __attribute__((ext_vector_type(4)));

__device__ inline unsigned short f2bf(float x) {
  unsigned u = __float_as_uint(x);
  return (unsigned short)((u + 0x7fffu + ((u >> 16) & 1u)) >> 16);
}
__device__ inline float bf2f(unsigned short s) { return __uint_as_float(((unsigned)s) << 16); }

__device__ inline int swz(int row, int colByte) { return row * 128 + (colByte ^ ((row & 7) << 4)); }

__device__ inline s8v ld8(const short* base, int row, int colByte) {
  return *(const s8v*)((const char*)base + swz(row, colByte));
}
__device__ inline void st4(short* base, int row, int colByte, s4v v) {
  *(s4v*)((char*)base + swz(row, colByte)) = v;
}
__device__ inline void st2(short* base, int row, int colByte, unsigned v) {
  *(unsigned*)((char*)base + swz(row, colByte)) = v;
}
__device__ inline void st1(short* base, int row, int colByte, unsigned short v) {
  *(short*)((char*)base + swz(row, colByte)) = (short)v;
}

__device__ inline void red16(float& x) {
  x += __shfl_xor(x, 1, 64);
  x += __shfl_xor(x, 2, 64);
  x += __shfl_xor(x, 4, 64);
  x += __shfl_xor(x, 8, 64);
}

__device__ inline f4v MM(s8v a, s8v b, f4v c) {
  return __builtin_amdgcn_mfma_f32_16x16x32_bf16(a, b, c, 0, 0, 0);
}
// 3-MFMA split product: (Ah+Al)(Bh+Bl) ~= Ah*Bh + Ah*Bl + Al*Bh
__device__ inline f4v MM3(s8v ah, s8v al, s8v bh, s8v bl, f4v c) {
  c = MM(ah, bh, c);
  c = MM(ah, bl, c);
  c = MM(al, bh, c);
  return c;
}

// ---------------- Kernel 1: per-chunk gradl + QK^T + decay + Intra + U^T.
// (unchanged from R13 champion)
__global__ __launch_bounds__(256, 2) void k_chunk(
    const float4* __restrict__ Q4, const float4* __restrict__ K4,
    const float* __restrict__ Kg, const float* __restrict__ Vg,
    const float* __restrict__ gate, const float* __restrict__ eta,
    const float4* __restrict__ W04, const float* __restrict__ gamma,
    const float* __restrict__ beta,
    float* __restrict__ Ut, float* __restrict__ Pg, float* __restrict__ Out)
{
  __shared__ __align__(16) short Khi[4096];
  __shared__ __align__(16) short Klo[4096];
  __shared__ __align__(16) short KtH[4096];
  __shared__ __align__(16) short KtL[4096];
  __shared__ __align__(16) short W0h[4096];
  __shared__ __align__(16) short W0l[4096];
  __shared__ float cl[64], wj[64];

  int tid = threadIdx.x;
  int bid = blockIdx.x;
  int h = bid & 15;            // XCD swizzle: bid%8 == h%8
  int c = bid >> 4;
  int rowb = h * L + c * 64;
  int R = tid >> 6, l = tid & 63, g = l >> 4, c16 = l & 15;
  int arow = 16 * R + c16;
  int kb0 = 16 * g, kb1 = 64 + 16 * g;

  float gv = gate[rowb + l];

  int g4 = tid & 15;
  float4 kA[2][2], wA[2][2];
  #pragma unroll
  for (int it = 0; it < 2; ++it) {
    int j0 = 2 * ((tid >> 4) + it * 16);
    kA[it][0] = K4[(size_t)(rowb + j0) * 16 + g4];
    kA[it][1] = K4[(size_t)(rowb + j0 + 1) * 16 + g4];
    wA[it][0] = W04[(size_t)h * 1024 + j0 * 16 + g4];
    wA[it][1] = W04[(size_t)h * 1024 + (j0 + 1) * 16 + g4];
  }

  const float4* qp = Q4 + (size_t)(rowb + arow) * 16;
  float4 qA0 = qp[2 * g], qA1 = qp[2 * g + 1], qA2 = qp[8 + 2 * g], qA3 = qp[8 + 2 * g + 1];
  float kk[4][4], vv[4][4], er[4];
  #pragma unroll
  for (int r = 0; r < 4; ++r) {
    int jr = 16 * R + 4 * g + r;
    const float* kp = Kg + (size_t)(rowb + jr) * 64 + c16;
    const float* vp = Vg + (size_t)(rowb + jr) * 64 + c16;
    #pragma unroll
    for (int ct = 0; ct < 4; ++ct) {
      kk[r][ct] = kp[16 * ct];
      vv[r][ct] = vp[16 * ct];
    }
    er[r] = eta[rowb + jr];
  }

  {
    float x = logf(fmaxf(gv, 1e-37f));
    #pragma unroll
    for (int off = 1; off < 64; off <<= 1) {
      float n = __shfl_up(x, off, 64);
      if (l >= off) x += n;
    }
    cl[l] = x;
    float c63 = __shfl(x, 63, 64);
    wj[l] = expf(c63 - x);
    if (R == 0) Pg[rowb + l] = expf(x);
  }

  #pragma unroll
  for (int it = 0; it < 2; ++it) {
    int j0 = 2 * ((tid >> 4) + it * 16);
    int j1 = j0 + 1;
    float w0j = wj[j0], w1j = wj[j1];
    float ke0[4] = {kA[it][0].x, kA[it][0].y, kA[it][0].z, kA[it][0].w};
    float ke1[4] = {kA[it][1].x, kA[it][1].y, kA[it][1].z, kA[it][1].w};
    float we0[4] = {wA[it][0].x, wA[it][0].y, wA[it][0].z, wA[it][0].w};
    float we1[4] = {wA[it][1].x, wA[it][1].y, wA[it][1].z, wA[it][1].w};
    s4v kh0, kl0, kh1, kl1;
    #pragma unroll
    for (int e = 0; e < 4; ++e) {
      unsigned short hb0 = f2bf(ke0[e]);
      kh0[e] = (short)hb0; kl0[e] = (short)f2bf(ke0[e] - bf2f(hb0));
      unsigned short hb1 = f2bf(ke1[e]);
      kh1[e] = (short)hb1; kl1[e] = (short)f2bf(ke1[e] - bf2f(hb1));
      int dr = 4 * g4 + e;
      float wk0 = ke0[e] * w0j, wk1 = ke1[e] * w1j;
      unsigned short th0 = f2bf(wk0), th1 = f2bf(wk1);
      st2(KtH, dr, 2 * j0, (unsigned)th0 | ((unsigned)th1 << 16));
      st2(KtL, dr, 2 * j0,
          (unsigned)f2bf(wk0 - bf2f(th0)) | ((unsigned)f2bf(wk1 - bf2f(th1)) << 16));
      unsigned short wh0 = f2bf(we0[e]), wh1 = f2bf(we1[e]);
      st2(W0h, dr, 2 * j0, (unsigned)wh0 | ((unsigned)wh1 << 16));
      st2(W0l, dr, 2 * j0,
          (unsigned)f2bf(we0[e] - bf2f(wh0)) | ((unsigned)f2bf(we1[e] - bf2f(wh1)) << 16));
    }
    st4(Khi, j0, 8 * g4, kh0); st4(Klo, j0, 8 * g4, kl0);
    st4(Khi, j1, 8 * g4, kh1); st4(Klo, j1, 8 * g4, kl1);
  }

  s8v aQh0, aQl0, aQh1, aQl1;
  {
    float q0[8] = {qA0.x, qA0.y, qA0.z, qA0.w, qA1.x, qA1.y, qA1.z, qA1.w};
    float q1[8] = {qA2.x, qA2.y, qA2.z, qA2.w, qA3.x, qA3.y, qA3.z, qA3.w};
    #pragma unroll
    for (int e = 0; e < 8; ++e) {
      unsigned short hb = f2bf(q0[e]);
      aQh0[e] = (short)hb; aQl0[e] = (short)f2bf(q0[e] - bf2f(hb));
      unsigned short hb1 = f2bf(q1[e]);
      aQh1[e] = (short)hb1; aQl1[e] = (short)f2bf(q1[e] - bf2f(hb1));
    }
  }
  __syncthreads();   // bar1: tiles staged

  f4v accS[4];
  #pragma unroll
  for (int ct = 0; ct < 4; ++ct) {
    int br = 16 * ct + c16;
    f4v a = {0.f, 0.f, 0.f, 0.f};
    a = MM3(aQh0, aQl0, ld8(Khi, br, kb0), ld8(Klo, br, kb0), a);
    a = MM3(aQh1, aQl1, ld8(Khi, br, kb1), ld8(Klo, br, kb1), a);
    accS[ct] = a;
  }

  s8v aKh0 = ld8(Khi, arow, kb0), aKh1 = ld8(Khi, arow, kb1);
  s8v aKl0 = ld8(Klo, arow, kb0), aKl1 = ld8(Klo, arow, kb1);
  f4v accZ[4];
  #pragma unroll
  for (int ct = 0; ct < 4; ++ct) {
    int br = 16 * ct + c16;
    f4v a = {0.f, 0.f, 0.f, 0.f};
    a = MM3(aKh0, aKl0, ld8(W0h, br, kb0), ld8(W0l, br, kb0), a);
    a = MM3(aKh1, aKl1, ld8(W0h, br, kb1), ld8(W0l, br, kb1), a);
    accZ[ct] = a;
  }

  float ga[4], be[4];
  #pragma unroll
  for (int ct = 0; ct < 4; ++ct) {
    ga[ct] = gamma[h * 64 + 16 * ct + c16];
    be[ct] = beta[h * 64 + 16 * ct + c16];
  }
  float gtreg[4][4];
  #pragma unroll
  for (int r = 0; r < 4; ++r) {
    float s1 = accZ[0][r] + accZ[1][r] + accZ[2][r] + accZ[3][r];
    red16(s1);
    float mu = s1 * (1.f / 64.f);
    float dv[4], s2 = 0.f;
    #pragma unroll
    for (int ct = 0; ct < 4; ++ct) { dv[ct] = accZ[ct][r] - mu; s2 += dv[ct] * dv[ct]; }
    red16(s2);
    float rstd = rsqrtf(s2 * (1.f / 64.f) + 1e-6f);
    float xh[4], gxh[4], t1 = 0.f, t2 = 0.f;
    #pragma unroll
    for (int ct = 0; ct < 4; ++ct) {
      xh[ct] = dv[ct] * rstd;
      float go = 2.f * (fmaf(ga[ct], xh[ct], be[ct]) + kk[r][ct] - vv[r][ct]);
      gxh[ct] = go * ga[ct];
      t1 += gxh[ct];
      t2 += gxh[ct] * xh[ct];
    }
    red16(t1);
    red16(t2);
    float m1 = t1 * (1.f / 64.f), m2 = t2 * (1.f / 64.f);
    #pragma unroll
    for (int ct = 0; ct < 4; ++ct)
      gtreg[r][ct] = -er[r] * (gxh[ct] - m1 - xh[ct] * m2) * rstd;
  }
  __syncthreads();   // bar2: K-row and W0 tiles dead

  #pragma unroll
  for (int ct = 0; ct < 4; ++ct) {
    s4v gh, gl;
    #pragma unroll
    for (int r = 0; r < 4; ++r) {
      unsigned short hb = f2bf(gtreg[r][ct]);
      gh[r] = (short)hb;
      gl[r] = (short)f2bf(gtreg[r][ct] - bf2f(hb));
    }
    st4(W0h, 16 * ct + c16, 2 * (16 * R + 4 * g), gh);
    st4(W0l, 16 * ct + c16, 2 * (16 * R + 4 * g), gl);
  }
  float cli[4];
  #pragma unroll
  for (int r = 0; r < 4; ++r) cli[r] = cl[16 * R + 4 * g + r];
  #pragma unroll
  for (int ct = 0; ct < 4; ++ct) {
    int j = 16 * ct + c16;
    float clj = cl[j];
    #pragma unroll
    for (int r = 0; r < 4; ++r) {
      int i = 16 * R + 4 * g + r;
      float s = (j <= i) ? accS[ct][r] * expf(cli[r] - clj) : 0.f;
      unsigned short hb = f2bf(s);
      st1(Khi, i, 2 * j, hb);
      st1(Klo, i, 2 * j, f2bf(s - bf2f(hb)));
    }
  }
  __syncthreads();   // bar3: S and gt^T visible

  s8v aSh0 = ld8(Khi, arow, kb0), aSh1 = ld8(Khi, arow, kb1);
  s8v aSl0 = ld8(Klo, arow, kb0), aSl1 = ld8(Klo, arow, kb1);
  #pragma unroll
  for (int ct = 0; ct < 4; ++ct) {
    int br = 16 * ct + c16;
    f4v a = {0.f, 0.f, 0.f, 0.f};
    a = MM3(aSh0, aSl0, ld8(W0h, br, kb0), ld8(W0l, br, kb0), a);
    a = MM3(aSh1, aSl1, ld8(W0h, br, kb1), ld8(W0l, br, kb1), a);
    #pragma unroll
    for (int r = 0; r < 4; ++r)
      Out[(size_t)(rowb + 16 * R + 4 * g + r) * 64 + br] = a[r];
  }

  float* ub = Ut + (size_t)(h * NC + c) * 4096;
  s8v aGh0 = ld8(W0h, arow, kb0), aGh1 = ld8(W0h, arow, kb1);
  s8v aGl0 = ld8(W0l, arow, kb0), aGl1 = ld8(W0l, arow, kb1);
  #pragma unroll
  for (int ct = 0; ct < 4; ++ct) {
    int br = 16 * ct + c16;
    f4v a = {0.f, 0.f, 0.f, 0.f};
    a = MM3(aGh0, aGl0, ld8(KtH, br, kb0), ld8(KtL, br, kb0), a);
    a = MM3(aGh1, aGl1, ld8(KtH, br, kb1), ld8(KtL, br, kb1), a);
    #pragma unroll
    for (int r = 0; r < 4; ++r)
      ub[(16 * R + 4 * g + r) * 64 + br] = a[r];
  }
}

// ---------------- Kernel 2: chunk-state scan, XCD-affine, full load hoist.
// The 32 Ut loads and 32 gate scalars are address-independent; only the fmaf
// chain is sequential. Hoist all loads before the recurrence: one latency
// wall instead of 32.
__global__ __launch_bounds__(256) void k_scan(
    const float* __restrict__ W0, const float* __restrict__ Ut,
    const float* __restrict__ Pg, float* __restrict__ Wpt)
{
  int bid = blockIdx.x;
  int h = bid & 15;            // bid%8 == h%8: scan runs on the XCD that owns Ut[h]
  int part = bid >> 4;
  int idx = part * 256 + threadIdx.x;   // [0, 4096)
  int erow = idx >> 6, d = idx & 63;

  float gc[NC];
  #pragma unroll
  for (int c2 = 0; c2 < NC; ++c2) gc[c2] = Pg[h * L + c2 * 64 + 63];
  float u[NC];
  const float* ub = Ut + (size_t)h * NC * 4096 + idx;
  #pragma unroll
  for (int c2 = 0; c2 < NC; ++c2) u[c2] = ub[c2 * 4096];
  float w = W0[h * 4096 + d * 64 + erow];   // W0^T element

  float* wb = Wpt + (size_t)h * NC * 4096 + idx;
  #pragma unroll
  for (int c2 = 0; c2 < NC; ++c2) {
    wb[c2 * 4096] = w;
    w = fmaf(gc[c2], w, u[c2]);
  }
}

// ---------------- Kernel 3: Zq = Pg*(q @ Wprev) + Intra ; LN fwd ; +q
// (R13 champion version: LDS-staged, 4 blocks/CU)
__global__ __launch_bounds__(256, 4) void k_out(
    const float4* __restrict__ Q4, const float* __restrict__ Qg,
    const float4* __restrict__ Wpt4, const float* __restrict__ Pg,
    const float* __restrict__ gamma, const float* __restrict__ beta,
    float* __restrict__ Out)
{
  __shared__ __align__(16) short Whi[4096];
  __shared__ __align__(16) short Wlo[4096];
  int tid = threadIdx.x;
  int bid = blockIdx.x;
  int h = bid & 15;            // same XCD swizzle
  int c = bid >> 4;
  int rowb = h * L + c * 64;
  int R = tid >> 6, l = tid & 63, g = l >> 4, c16 = l & 15;
  int arow = 16 * R + c16;
  int kb0 = 16 * g, kb1 = 64 + 16 * g;

  // ---- staging loads first (L2-local Wpt)
  float4 wv0 = Wpt4[(size_t)(h * NC + c) * 1024 + tid];
  float4 wv1 = Wpt4[(size_t)(h * NC + c) * 1024 + tid + 256];
  float4 wv2 = Wpt4[(size_t)(h * NC + c) * 1024 + tid + 512];
  float4 wv3 = Wpt4[(size_t)(h * NC + c) * 1024 + tid + 768];

  // ---- prefetches
  const float4* qp = Q4 + (size_t)(rowb + arow) * 16;
  float4 qA0 = qp[2 * g], qA1 = qp[2 * g + 1], qA2 = qp[8 + 2 * g], qA3 = qp[8 + 2 * g + 1];
  float io[4][4], qres[4][4], pr[4];
  #pragma unroll
  for (int r = 0; r < 4; ++r) {
    int row = rowb + 16 * R + 4 * g + r;
    pr[r] = Pg[row];
    #pragma unroll
    for (int ct = 0; ct < 4; ++ct) {
      io[r][ct] = Out[(size_t)row * 64 + 16 * ct + c16];
      qres[r][ct] = Qg[(size_t)row * 64 + 16 * ct + c16];
    }
  }

  // ---- stage Wprev^T split into LDS
  float4 wvs[4] = {wv0, wv1, wv2, wv3};
  #pragma unroll
  for (int j = 0; j < 4; ++j) {
    int f4i = tid + j * 256;
    float we[4] = {wvs[j].x, wvs[j].y, wvs[j].z, wvs[j].w};
    s4v wh, wl;
    #pragma unroll
    for (int e = 0; e < 4; ++e) {
      unsigned short hb = f2bf(we[e]);
      wh[e] = (short)hb;
      wl[e] = (short)f2bf(we[e] - bf2f(hb));
    }
    st4(Whi, f4i >> 4, 8 * (f4i & 15), wh);
    st4(Wlo, f4i >> 4, 8 * (f4i & 15), wl);
  }

  // ---- split q A-fragments in registers
  s8v ah0, al0, ah1, al1;
  {
    float q0[8] = {qA0.x, qA0.y, qA0.z, qA0.w, qA1.x, qA1.y, qA1.z, qA1.w};
    float q1[8] = {qA2.x, qA2.y, qA2.z, qA2.w, qA3.x, qA3.y, qA3.z, qA3.w};
    #pragma unroll
    for (int e = 0; e < 8; ++e) {
      unsigned short hb = f2bf(q0[e]);
      ah0[e] = (short)hb; al0[e] = (short)f2bf(q0[e] - bf2f(hb));
      unsigned short hb1 = f2bf(q1[e]);
      ah1[e] = (short)hb1; al1[e] = (short)f2bf(q1[e] - bf2f(hb1));
    }
  }
  __syncthreads();

  f4v acc[4];
  #pragma unroll
  for (int ct = 0; ct < 4; ++ct) {
    int br = 16 * ct + c16;
    f4v a = {0.f, 0.f, 0.f, 0.f};
    a = MM3(ah0, al0, ld8(Whi, br, kb0), ld8(Wlo, br, kb0), a);
    a = MM3(ah1, al1, ld8(Whi, br, kb1), ld8(Wlo, br, kb1), a);
    acc[ct] = a;
  }
  float ga[4], be[4];
  #pragma unroll
  for (int ct = 0; ct < 4; ++ct) {
    ga[ct] = gamma[h * 64 + 16 * ct + c16];
    be[ct] = beta[h * 64 + 16 * ct + c16];
  }
  #pragma unroll
  for (int r = 0; r < 4; ++r) {
    int row = rowb + 16 * R + 4 * g + r;
    float zq[4];
    #pragma unroll
    for (int ct = 0; ct < 4; ++ct)
      zq[ct] = fmaf(pr[r], acc[ct][r], io[r][ct]);
    float s1 = zq[0] + zq[1] + zq[2] + zq[3];
    red16(s1);
    float mu = s1 * (1.f / 64.f);
    float dv[4], s2 = 0.f;
    #pragma unroll
    for (int ct = 0; ct < 4; ++ct) { dv[ct] = zq[ct] - mu; s2 += dv[ct] * dv[ct]; }
    red16(s2);
    float rstd = rsqrtf(s2 * (1.f / 64.f) + 1e-6f);
    #pragma unroll
    for (int ct = 0; ct < 4; ++ct) {
      float o = fmaf(ga[ct], dv[ct] * rstd, be[ct]) + qres[r][ct];
      Out[(size_t)row * 64 + 16 * ct + c16] = o;
    }
  }
}

extern "C" void kernel_launch(void* const* d_in, const int* in_sizes, int n_in,
                              void* d_out, int out_size, void* d_ws, size_t ws_size,
                              hipStream_t stream) {
  const float* q     = (const float*)d_in[0];
  const float* k     = (const float*)d_in[1];
  const float* v     = (const float*)d_in[2];
  const float* gate  = (const float*)d_in[3];
  const float* eta   = (const float*)d_in[4];
  const float* W0    = (const float*)d_in[5];
  const float* gamma = (const float*)d_in[6];
  const float* beta  = (const float*)d_in[7];
  float* out = (float*)d_out;
  float* ws  = (float*)d_ws;

  float* Pg  = ws;                         // 32768 floats
  float* Ut  = ws + 32768;                 // 2097152 floats
  float* Wpt = ws + 32768 + 2097152;       // 2097152 floats

  k_chunk<<<H * NC, 256, 0, stream>>>(
      (const float4*)q, (const float4*)k, k, v, gate, eta,
      (const float4*)W0, gamma, beta, Ut, Pg, out);
  k_scan<<<256, 256, 0, stream>>>(W0, Ut, Pg, Wpt);
  k_out<<<H * NC, 256, 0, stream>>>(
      (const float4*)q, q, (const float4*)Wpt, Pg, gamma, beta, out);
}

// Round 16
// 29.981 us; speedup vs baseline: 1.0571x; 1.0041x over previous
//
#include <hip/hip_runtime.h>
#include <hip/hip_bf16.h>
#include <math.h>

// B=1, H=16, L=2048, D=64. Chunked gated recurrence, chunk C=64, NC=32.
// R15 champion (3 dispatches, XCD affinity bid=c*16+h, load-order discipline,
// k_scan full load-hoist, k_out LDS-staged at 4 blocks/CU) + this round:
// k_chunk eliminates its 36 scattered scalar VMEM loads: (k - v) is computed
// during staging (v loaded as coalesced float4) into an fp32 LDS tile
// [64][68] (2-way bank aliasing = free); LN reads it as LDS scalars; eta is
// one aligned float4. Head VMEM instructions/thread: 53 -> 25, all coalesced.
// All 64^3 matmuls: v_mfma_f32_16x16x32_bf16, FULL hi/lo split-bf16 (3-MFMA
// emulation ~2^-17 rel err) on every operand (LN amplifies relative error).
// k_chunk LDS: 6 bf16 tiles [64][128B] XOR-swizzled (byte ^= (row&7)<<4)
// + fp32 diff tile = 67 KB -> 2 blocks/CU.
// A row-major [M][K], B transposed [N][K]: one ds_read_b128 per fragment.
// C/D: row=4*(l>>4)+reg, col=l&15 (m89-verified).

#define H 16
#define L 2048
#define D 64
#define NC 32

typedef short s8v __attribute__((ext_vector_type(8)));
typedef short s4v __attribute__((ext_vector_type(4)));
typedef float f4v __attribute__((ext_vector_type(4)));

__device__ inline unsigned short f2bf(float x) {
  unsigned u = __float_as_uint(x);
  return (unsigned short)((u + 0x7fffu + ((u >> 16) & 1u)) >> 16);
}
__device__ inline float bf2f(unsigned short s) { return __uint_as_float(((unsigned)s) << 16); }

__device__ inline int swz(int row, int colByte) { return row * 128 + (colByte ^ ((row & 7) << 4)); }

__device__ inline s8v ld8(const short* base, int row, int colByte) {
  return *(const s8v*)((const char*)base + swz(row, colByte));
}
__device__ inline void st4(short* base, int row, int colByte, s4v v) {
  *(s4v*)((char*)base + swz(row, colByte)) = v;
}
__device__ inline void st2(short* base, int row, int colByte, unsigned v) {
  *(unsigned*)((char*)base + swz(row, colByte)) = v;
}
__device__ inline void st1(short* base, int row, int colByte, unsigned short v) {
  *(short*)((char*)base + swz(row, colByte)) = (short)v;
}

__device__ inline void red16(float& x) {
  x += __shfl_xor(x, 1, 64);
  x += __shfl_xor(x, 2, 64);
  x += __shfl_xor(x, 4, 64);
  x += __shfl_xor(x, 8, 64);
}

__device__ inline f4v MM(s8v a, s8v b, f4v c) {
  return __builtin_amdgcn_mfma_f32_16x16x32_bf16(a, b, c, 0, 0, 0);
}
// 3-MFMA split product: (Ah+Al)(Bh+Bl) ~= Ah*Bh + Ah*Bl + Al*Bh
__device__ inline f4v MM3(s8v ah, s8v al, s8v bh, s8v bl, f4v c) {
  c = MM(ah, bh, c);
  c = MM(ah, bl, c);
  c = MM(al, bh, c);
  return c;
}

// ---------------- Kernel 1: per-chunk gradl + QK^T + decay + Intra + U^T.
__global__ __launch_bounds__(256, 2) void k_chunk(
    const float4* __restrict__ Q4, const float4* __restrict__ K4,
    const float4* __restrict__ V4, const float* __restrict__ gate,
    const float* __restrict__ eta, const float4* __restrict__ W04,
    const float* __restrict__ gamma, const float* __restrict__ beta,
    float* __restrict__ Ut, float* __restrict__ Pg, float* __restrict__ Out)
{
  __shared__ __align__(16) short Khi[4096];  // k rows hi (A M2; B M1); after bar2: S hi
  __shared__ __align__(16) short Klo[4096];  // k rows lo;              after bar2: S lo
  __shared__ __align__(16) short KtH[4096];  // (wj*k)^T [d][j] hi (B M4)
  __shared__ __align__(16) short KtL[4096];  // (wj*k)^T [d][j] lo
  __shared__ __align__(16) short W0h[4096];  // W0^T [e][d] hi (B M2); after bar2: gt^T hi
  __shared__ __align__(16) short W0l[4096];  // W0^T [e][d] lo;        after bar2: gt^T lo
  __shared__ __align__(16) float Dkv[64 * 68];  // (k - v) fp32, pitch 68
  __shared__ float cl[64], wj[64];

  int tid = threadIdx.x;
  int bid = blockIdx.x;
  int h = bid & 15;            // XCD swizzle: bid%8 == h%8
  int c = bid >> 4;
  int rowb = h * L + c * 64;
  int R = tid >> 6, l = tid & 63, g = l >> 4, c16 = l & 15;
  int arow = 16 * R + c16;
  int kb0 = 16 * g, kb1 = 64 + 16 * g;

  // ---- gate load first (cumsum consumes it soonest)
  float gv = gate[rowb + l];

  // ---- staging loads next: first vmcnt waits drain only these
  int g4 = tid & 15;
  float4 kA[2][2], wA[2][2], vA[2][2];
  #pragma unroll
  for (int it = 0; it < 2; ++it) {
    int j0 = 2 * ((tid >> 4) + it * 16);
    kA[it][0] = K4[(size_t)(rowb + j0) * 16 + g4];
    kA[it][1] = K4[(size_t)(rowb + j0 + 1) * 16 + g4];
    vA[it][0] = V4[(size_t)(rowb + j0) * 16 + g4];
    vA[it][1] = V4[(size_t)(rowb + j0 + 1) * 16 + g4];
    wA[it][0] = W04[(size_t)h * 1024 + j0 * 16 + g4];
    wA[it][1] = W04[(size_t)h * 1024 + (j0 + 1) * 16 + g4];
  }

  // ---- prefetches (all coalesced float4)
  const float4* qp = Q4 + (size_t)(rowb + arow) * 16;
  float4 qA0 = qp[2 * g], qA1 = qp[2 * g + 1], qA2 = qp[8 + 2 * g], qA3 = qp[8 + 2 * g + 1];
  float4 er4 = *(const float4*)(eta + rowb + 16 * R + 4 * g);
  const float er[4] = {er4.x, er4.y, er4.z, er4.w};

  // ---- gate log-cumsum (redundant per wave; wave reads only its own writes)
  {
    float x = logf(fmaxf(gv, 1e-37f));
    #pragma unroll
    for (int off = 1; off < 64; off <<= 1) {
      float n = __shfl_up(x, off, 64);
      if (l >= off) x += n;
    }
    cl[l] = x;
    float c63 = __shfl(x, 63, 64);
    wj[l] = expf(c63 - x);
    if (R == 0) Pg[rowb + l] = expf(x);
  }

  // ---- stage: k rows hi/lo, (wj*k)^T, W0^T, and (k - v) fp32 tile
  #pragma unroll
  for (int it = 0; it < 2; ++it) {
    int j0 = 2 * ((tid >> 4) + it * 16);
    int j1 = j0 + 1;
    float w0j = wj[j0], w1j = wj[j1];
    float ke0[4] = {kA[it][0].x, kA[it][0].y, kA[it][0].z, kA[it][0].w};
    float ke1[4] = {kA[it][1].x, kA[it][1].y, kA[it][1].z, kA[it][1].w};
    float we0[4] = {wA[it][0].x, wA[it][0].y, wA[it][0].z, wA[it][0].w};
    float we1[4] = {wA[it][1].x, wA[it][1].y, wA[it][1].z, wA[it][1].w};
    float4 d0, d1;
    d0.x = kA[it][0].x - vA[it][0].x; d0.y = kA[it][0].y - vA[it][0].y;
    d0.z = kA[it][0].z - vA[it][0].z; d0.w = kA[it][0].w - vA[it][0].w;
    d1.x = kA[it][1].x - vA[it][1].x; d1.y = kA[it][1].y - vA[it][1].y;
    d1.z = kA[it][1].z - vA[it][1].z; d1.w = kA[it][1].w - vA[it][1].w;
    *(float4*)&Dkv[j0 * 68 + 4 * g4] = d0;
    *(float4*)&Dkv[j1 * 68 + 4 * g4] = d1;
    s4v kh0, kl0, kh1, kl1;
    #pragma unroll
    for (int e = 0; e < 4; ++e) {
      unsigned short hb0 = f2bf(ke0[e]);
      kh0[e] = (short)hb0; kl0[e] = (short)f2bf(ke0[e] - bf2f(hb0));
      unsigned short hb1 = f2bf(ke1[e]);
      kh1[e] = (short)hb1; kl1[e] = (short)f2bf(ke1[e] - bf2f(hb1));
      int dr = 4 * g4 + e;
      float wk0 = ke0[e] * w0j, wk1 = ke1[e] * w1j;
      unsigned short th0 = f2bf(wk0), th1 = f2bf(wk1);
      st2(KtH, dr, 2 * j0, (unsigned)th0 | ((unsigned)th1 << 16));
      st2(KtL, dr, 2 * j0,
          (unsigned)f2bf(wk0 - bf2f(th0)) | ((unsigned)f2bf(wk1 - bf2f(th1)) << 16));
      unsigned short wh0 = f2bf(we0[e]), wh1 = f2bf(we1[e]);
      st2(W0h, dr, 2 * j0, (unsigned)wh0 | ((unsigned)wh1 << 16));
      st2(W0l, dr, 2 * j0,
          (unsigned)f2bf(we0[e] - bf2f(wh0)) | ((unsigned)f2bf(we1[e] - bf2f(wh1)) << 16));
    }
    st4(Khi, j0, 8 * g4, kh0); st4(Klo, j0, 8 * g4, kl0);
    st4(Khi, j1, 8 * g4, kh1); st4(Klo, j1, 8 * g4, kl1);
  }

  // ---- split q A-fragments in registers (no LDS)
  s8v aQh0, aQl0, aQh1, aQl1;
  {
    float q0[8] = {qA0.x, qA0.y, qA0.z, qA0.w, qA1.x, qA1.y, qA1.z, qA1.w};
    float q1[8] = {qA2.x, qA2.y, qA2.z, qA2.w, qA3.x, qA3.y, qA3.z, qA3.w};
    #pragma unroll
    for (int e = 0; e < 8; ++e) {
      unsigned short hb = f2bf(q0[e]);
      aQh0[e] = (short)hb; aQl0[e] = (short)f2bf(q0[e] - bf2f(hb));
      unsigned short hb1 = f2bf(q1[e]);
      aQh1[e] = (short)hb1; aQl1[e] = (short)f2bf(q1[e] - bf2f(hb1));
    }
  }
  __syncthreads();   // bar1: tiles staged

  // ---- M1: S = QK^T (split x split)
  f4v accS[4];
  #pragma unroll
  for (int ct = 0; ct < 4; ++ct) {
    int br = 16 * ct + c16;
    f4v a = {0.f, 0.f, 0.f, 0.f};
    a = MM3(aQh0, aQl0, ld8(Khi, br, kb0), ld8(Klo, br, kb0), a);
    a = MM3(aQh1, aQl1, ld8(Khi, br, kb1), ld8(Klo, br, kb1), a);
    accS[ct] = a;
  }

  // ---- M2: Z1 = K @ W0 (split x split)
  s8v aKh0 = ld8(Khi, arow, kb0), aKh1 = ld8(Khi, arow, kb1);
  s8v aKl0 = ld8(Klo, arow, kb0), aKl1 = ld8(Klo, arow, kb1);
  f4v accZ[4];
  #pragma unroll
  for (int ct = 0; ct < 4; ++ct) {
    int br = 16 * ct + c16;
    f4v a = {0.f, 0.f, 0.f, 0.f};
    a = MM3(aKh0, aKl0, ld8(W0h, br, kb0), ld8(W0l, br, kb0), a);
    a = MM3(aKh1, aKl1, ld8(W0h, br, kb1), ld8(W0l, br, kb1), a);
    accZ[ct] = a;
  }

  // ---- LN-L2 backward; (k-v) from LDS, eta in regs
  float ga[4], be[4];
  #pragma unroll
  for (int ct = 0; ct < 4; ++ct) {
    ga[ct] = gamma[h * 64 + 16 * ct + c16];
    be[ct] = beta[h * 64 + 16 * ct + c16];
  }
  float gtreg[4][4];
  #pragma unroll
  for (int r = 0; r < 4; ++r) {
    int jr = 16 * R + 4 * g + r;
    float s1 = accZ[0][r] + accZ[1][r] + accZ[2][r] + accZ[3][r];
    red16(s1);
    float mu = s1 * (1.f / 64.f);
    float dv[4], s2 = 0.f;
    #pragma unroll
    for (int ct = 0; ct < 4; ++ct) { dv[ct] = accZ[ct][r] - mu; s2 += dv[ct] * dv[ct]; }
    red16(s2);
    float rstd = rsqrtf(s2 * (1.f / 64.f) + 1e-6f);
    float xh[4], gxh[4], t1 = 0.f, t2 = 0.f;
    #pragma unroll
    for (int ct = 0; ct < 4; ++ct) {
      xh[ct] = dv[ct] * rstd;
      float dkv = Dkv[jr * 68 + 16 * ct + c16];
      float go = 2.f * (fmaf(ga[ct], xh[ct], be[ct]) + dkv);
      gxh[ct] = go * ga[ct];
      t1 += gxh[ct];
      t2 += gxh[ct] * xh[ct];
    }
    red16(t1);
    red16(t2);
    float m1 = t1 * (1.f / 64.f), m2 = t2 * (1.f / 64.f);
    #pragma unroll
    for (int ct = 0; ct < 4; ++ct)
      gtreg[r][ct] = -er[r] * (gxh[ct] - m1 - xh[ct] * m2) * rstd;
  }
  __syncthreads();   // bar2: K-row and W0 tiles dead

  // ---- gt^T split into W0 tiles (st4-packed along j); S split into K tiles
  #pragma unroll
  for (int ct = 0; ct < 4; ++ct) {
    s4v gh, gl;
    #pragma unroll
    for (int r = 0; r < 4; ++r) {
      unsigned short hb = f2bf(gtreg[r][ct]);
      gh[r] = (short)hb;
      gl[r] = (short)f2bf(gtreg[r][ct] - bf2f(hb));
    }
    st4(W0h, 16 * ct + c16, 2 * (16 * R + 4 * g), gh);
    st4(W0l, 16 * ct + c16, 2 * (16 * R + 4 * g), gl);
  }
  float cli[4];
  #pragma unroll
  for (int r = 0; r < 4; ++r) cli[r] = cl[16 * R + 4 * g + r];
  #pragma unroll
  for (int ct = 0; ct < 4; ++ct) {
    int j = 16 * ct + c16;
    float clj = cl[j];
    #pragma unroll
    for (int r = 0; r < 4; ++r) {
      int i = 16 * R + 4 * g + r;
      float s = (j <= i) ? accS[ct][r] * expf(cli[r] - clj) : 0.f;
      unsigned short hb = f2bf(s);
      st1(Khi, i, 2 * j, hb);
      st1(Klo, i, 2 * j, f2bf(s - bf2f(hb)));
    }
  }
  __syncthreads();   // bar3: S and gt^T visible

  // ---- M3: Intra[i][e] = S·gt -> Out
  s8v aSh0 = ld8(Khi, arow, kb0), aSh1 = ld8(Khi, arow, kb1);
  s8v aSl0 = ld8(Klo, arow, kb0), aSl1 = ld8(Klo, arow, kb1);
  #pragma unroll
  for (int ct = 0; ct < 4; ++ct) {
    int br = 16 * ct + c16;
    f4v a = {0.f, 0.f, 0.f, 0.f};
    a = MM3(aSh0, aSl0, ld8(W0h, br, kb0), ld8(W0l, br, kb0), a);
    a = MM3(aSh1, aSl1, ld8(W0h, br, kb1), ld8(W0l, br, kb1), a);
    #pragma unroll
    for (int r = 0; r < 4; ++r)
      Out[(size_t)(rowb + 16 * R + 4 * g + r) * 64 + br] = a[r];
  }

  // ---- M4: U^T[e][d] = gt^T · (wj*k)^T -> Ut (indexed (h,c))
  float* ub = Ut + (size_t)(h * NC + c) * 4096;
  s8v aGh0 = ld8(W0h, arow, kb0), aGh1 = ld8(W0h, arow, kb1);
  s8v aGl0 = ld8(W0l, arow, kb0), aGl1 = ld8(W0l, arow, kb1);
  #pragma unroll
  for (int ct = 0; ct < 4; ++ct) {
    int br = 16 * ct + c16;
    f4v a = {0.f, 0.f, 0.f, 0.f};
    a = MM3(aGh0, aGl0, ld8(KtH, br, kb0), ld8(KtL, br, kb0), a);
    a = MM3(aGh1, aGl1, ld8(KtH, br, kb1), ld8(KtL, br, kb1), a);
    #pragma unroll
    for (int r = 0; r < 4; ++r)
      ub[(16 * R + 4 * g + r) * 64 + br] = a[r];
  }
}

// ---------------- Kernel 2: chunk-state scan, XCD-affine, full load hoist.
__global__ __launch_bounds__(256) void k_scan(
    const float* __restrict__ W0, const float* __restrict__ Ut,
    const float* __restrict__ Pg, float* __restrict__ Wpt)
{
  int bid = blockIdx.x;
  int h = bid & 15;            // bid%8 == h%8: scan runs on the XCD that owns Ut[h]
  int part = bid >> 4;
  int idx = part * 256 + threadIdx.x;   // [0, 4096)
  int erow = idx >> 6, d = idx & 63;

  float gc[NC];
  #pragma unroll
  for (int c2 = 0; c2 < NC; ++c2) gc[c2] = Pg[h * L + c2 * 64 + 63];
  float u[NC];
  const float* ub = Ut + (size_t)h * NC * 4096 + idx;
  #pragma unroll
  for (int c2 = 0; c2 < NC; ++c2) u[c2] = ub[c2 * 4096];
  float w = W0[h * 4096 + d * 64 + erow];   // W0^T element

  float* wb = Wpt + (size_t)h * NC * 4096 + idx;
  #pragma unroll
  for (int c2 = 0; c2 < NC; ++c2) {
    wb[c2 * 4096] = w;
    w = fmaf(gc[c2], w, u[c2]);
  }
}

// ---------------- Kernel 3: Zq = Pg*(q @ Wprev) + Intra ; LN fwd ; +q
// (R15 champion version: LDS-staged, 4 blocks/CU)
__global__ __launch_bounds__(256, 4) void k_out(
    const float4* __restrict__ Q4, const float* __restrict__ Qg,
    const float4* __restrict__ Wpt4, const float* __restrict__ Pg,
    const float* __restrict__ gamma, const float* __restrict__ beta,
    float* __restrict__ Out)
{
  __shared__ __align__(16) short Whi[4096];
  __shared__ __align__(16) short Wlo[4096];
  int tid = threadIdx.x;
  int bid = blockIdx.x;
  int h = bid & 15;            // same XCD swizzle
  int c = bid >> 4;
  int rowb = h * L + c * 64;
  int R = tid >> 6, l = tid & 63, g = l >> 4, c16 = l & 15;
  int arow = 16 * R + c16;
  int kb0 = 16 * g, kb1 = 64 + 16 * g;

  // ---- staging loads first (L2-local Wpt)
  float4 wv0 = Wpt4[(size_t)(h * NC + c) * 1024 + tid];
  float4 wv1 = Wpt4[(size_t)(h * NC + c) * 1024 + tid + 256];
  float4 wv2 = Wpt4[(size_t)(h * NC + c) * 1024 + tid + 512];
  float4 wv3 = Wpt4[(size_t)(h * NC + c) * 1024 + tid + 768];

  // ---- prefetches
  const float4* qp = Q4 + (size_t)(rowb + arow) * 16;
  float4 qA0 = qp[2 * g], qA1 = qp[2 * g + 1], qA2 = qp[8 + 2 * g], qA3 = qp[8 + 2 * g + 1];
  float io[4][4], qres[4][4], pr[4];
  #pragma unroll
  for (int r = 0; r < 4; ++r) {
    int row = rowb + 16 * R + 4 * g + r;
    pr[r] = Pg[row];
    #pragma unroll
    for (int ct = 0; ct < 4; ++ct) {
      io[r][ct] = Out[(size_t)row * 64 + 16 * ct + c16];
      qres[r][ct] = Qg[(size_t)row * 64 + 16 * ct + c16];
    }
  }

  // ---- stage Wprev^T split into LDS
  float4 wvs[4] = {wv0, wv1, wv2, wv3};
  #pragma unroll
  for (int j = 0; j < 4; ++j) {
    int f4i = tid + j * 256;
    float we[4] = {wvs[j].x, wvs[j].y, wvs[j].z, wvs[j].w};
    s4v wh, wl;
    #pragma unroll
    for (int e = 0; e < 4; ++e) {
      unsigned short hb = f2bf(we[e]);
      wh[e] = (short)hb;
      wl[e] = (short)f2bf(we[e] - bf2f(hb));
    }
    st4(Whi, f4i >> 4, 8 * (f4i & 15), wh);
    st4(Wlo, f4i >> 4, 8 * (f4i & 15), wl);
  }

  // ---- split q A-fragments in registers
  s8v ah0, al0, ah1, al1;
  {
    float q0[8] = {qA0.x, qA0.y, qA0.z, qA0.w, qA1.x, qA1.y, qA1.z, qA1.w};
    float q1[8] = {qA2.x, qA2.y, qA2.z, qA2.w, qA3.x, qA3.y, qA3.z, qA3.w};
    #pragma unroll
    for (int e = 0; e < 8; ++e) {
      unsigned short hb = f2bf(q0[e]);
      ah0[e] = (short)hb; al0[e] = (short)f2bf(q0[e] - bf2f(hb));
      unsigned short hb1 = f2bf(q1[e]);
      ah1[e] = (short)hb1; al1[e] = (short)f2bf(q1[e] - bf2f(hb1));
    }
  }
  __syncthreads();

  f4v acc[4];
  #pragma unroll
  for (int ct = 0; ct < 4; ++ct) {
    int br = 16 * ct + c16;
    f4v a = {0.f, 0.f, 0.f, 0.f};
    a = MM3(ah0, al0, ld8(Whi, br, kb0), ld8(Wlo, br, kb0), a);
    a = MM3(ah1, al1, ld8(Whi, br, kb1), ld8(Wlo, br, kb1), a);
    acc[ct] = a;
  }
  float ga[4], be[4];
  #pragma unroll
  for (int ct = 0; ct < 4; ++ct) {
    ga[ct] = gamma[h * 64 + 16 * ct + c16];
    be[ct] = beta[h * 64 + 16 * ct + c16];
  }
  #pragma unroll
  for (int r = 0; r < 4; ++r) {
    int row = rowb + 16 * R + 4 * g + r;
    float zq[4];
    #pragma unroll
    for (int ct = 0; ct < 4; ++ct)
      zq[ct] = fmaf(pr[r], acc[ct][r], io[r][ct]);
    float s1 = zq[0] + zq[1] + zq[2] + zq[3];
    red16(s1);
    float mu = s1 * (1.f / 64.f);
    float dv[4], s2 = 0.f;
    #pragma unroll
    for (int ct = 0; ct < 4; ++ct) { dv[ct] = zq[ct] - mu; s2 += dv[ct] * dv[ct]; }
    red16(s2);
    float rstd = rsqrtf(s2 * (1.f / 64.f) + 1e-6f);
    #pragma unroll
    for (int ct = 0; ct < 4; ++ct) {
      float o = fmaf(ga[ct], dv[ct] * rstd, be[ct]) + qres[r][ct];
      Out[(size_t)row * 64 + 16 * ct + c16] = o;
    }
  }
}

extern "C" void kernel_launch(void* const* d_in, const int* in_sizes, int n_in,
                              void* d_out, int out_size, void* d_ws, size_t ws_size,
                              hipStream_t stream) {
  const float* q     = (const float*)d_in[0];
  const float* k     = (const float*)d_in[1];
  const float* v     = (const float*)d_in[2];
  const float* gate  = (const float*)d_in[3];
  const float* eta   = (const float*)d_in[4];
  const float* W0    = (const float*)d_in[5];
  const float* gamma = (const float*)d_in[6];
  const float* beta  = (const float*)d_in[7];
  float* out = (float*)d_out;
  float* ws  = (float*)d_ws;

  float* Pg  = ws;                         // 32768 floats
  float* Ut  = ws + 32768;                 // 2097152 floats
  float* Wpt = ws + 32768 + 2097152;       // 2097152 floats

  k_chunk<<<H * NC, 256, 0, stream>>>(
      (const float4*)q, (const float4*)k, (const float4*)v, gate, eta,
      (const float4*)W0, gamma, beta, Ut, Pg, out);
  k_scan<<<256, 256, 0, stream>>>(W0, Ut, Pg, Wpt);
  k_out<<<H * NC, 256, 0, stream>>>(
      (const float4*)q, q, (const float4*)Wpt, Pg, gamma, beta, out);
}